// Round 1
// baseline (65.528 us; speedup 1.0000x reference)
//
#include <hip/hip_runtime.h>
#include <hip/hip_bf16.h>
#include <math.h>

// Problem constants
// B=128, F_IN=1000, D=512, K=10, C=5, T=1000, TAU=0.1
//
// Algebraic contraction:
//   logits_s[b,t,k] = sum_c v_t[b,c,t] * M[b,c,k],  M[b,c,k] = sum_d h[b,c,d]*W_mlp[d,k]
// removes the (B,D,T) intermediate entirely (~2 GFLOP -> ~20 MFLOP).
//
// All fp32 (no fp32 MFMA on CDNA4; bf16 would amplify through sigmoid(x/0.1)).

// ---------------- transpose feats (128,1000) -> featsT (1000,128) ----------------
__global__ __launch_bounds__(256) void kT(const float* __restrict__ feats,
                                          float* __restrict__ featsT) {
    int i = blockIdx.x * 256 + threadIdx.x;   // < 128000
    if (i >= 128000) return;
    int b = i & 127, k = i >> 7;
    featsT[i] = feats[b * 1000 + k];
}

// ---------------- adapt GEMM: r_b = relu(feats @ W_adapt + b_adapt) --------------
// k-split partials: pA[s][e][b], s=0..7 (125 k each). Lanes = b (coalesced),
// weights are wave-uniform -> scalar loads.
__global__ __launch_bounds__(128) void kA(const float* __restrict__ featsT,
                                          const float* __restrict__ W_adapt,
                                          float* __restrict__ pA) {
    int b  = threadIdx.x;           // 0..127
    int e0 = blockIdx.x * 8;        // 64 e-chunks
    int s  = blockIdx.y;            // 8 k-splits
    int k0 = s * 125;
    float acc[8] = {};
    for (int k = 0; k < 125; ++k) {
        float f = featsT[(k0 + k) * 128 + b];
        const float* w = &W_adapt[(k0 + k) * 512 + e0];
        #pragma unroll
        for (int j = 0; j < 8; ++j) acc[j] = fmaf(f, w[j], acc[j]);
    }
    #pragma unroll
    for (int j = 0; j < 8; ++j) pA[(s * 512 + e0 + j) * 128 + b] = acc[j];
}

__global__ __launch_bounds__(256) void kRA(const float* __restrict__ pA,
                                           const float* __restrict__ b_adapt,
                                           float* __restrict__ r_bT) {
    int i = blockIdx.x * 256 + threadIdx.x;   // < 65536 = D*B
    int e = i >> 7;
    float acc = b_adapt[e];
    #pragma unroll
    for (int s = 0; s < 8; ++s) acc += pA[s * 65536 + i];
    r_bT[i] = fmaxf(acc, 0.f);                // r_bT[e][b]
}

// ---------------- channel GEMM: h[b,c,e] = relu(sum_d r_b[b,d]*W_ch[c,d,e]+b_ch) --
// d-split partials: pB[s][c][e][b], s=0..3 (128 d each).
__global__ __launch_bounds__(128) void kB(const float* __restrict__ r_bT,
                                          const float* __restrict__ W_ch,
                                          float* __restrict__ pB) {
    int b  = threadIdx.x;
    int e0 = blockIdx.x * 16;       // 32 e-chunks
    int s  = blockIdx.y;            // 4 d-splits
    int c  = blockIdx.z;            // 5
    int d0 = s * 128;
    float acc[16] = {};
    for (int d = 0; d < 128; ++d) {
        float f = r_bT[(d0 + d) * 128 + b];
        const float* w = &W_ch[((size_t)(c * 512 + d0 + d)) * 512 + e0];
        #pragma unroll
        for (int j = 0; j < 16; ++j) acc[j] = fmaf(f, w[j], acc[j]);
    }
    #pragma unroll
    for (int j = 0; j < 16; ++j)
        pB[((s * 5 + c) * 512 + e0 + j) * 128 + b] = acc[j];
}

__global__ __launch_bounds__(256) void kRB(const float* __restrict__ pB,
                                           const float* __restrict__ b_ch,
                                           float* __restrict__ hT) {
    int i = blockIdx.x * 256 + threadIdx.x;   // < 327680 = C*D*B
    int cd = i >> 7;                          // c*512+e
    float acc = b_ch[cd];
    #pragma unroll
    for (int s = 0; s < 4; ++s) acc += pB[s * 327680 + i];
    hT[i] = fmaxf(acc, 0.f);                  // hT[c][e][b]
}

// ---------------- gate logits + M partials ---------------------------------------
// pg[s][c][b] = partial gate dot, pM[s][c][k][b] = partial M. d-split 8 (64 each).
__global__ __launch_bounds__(128) void kG(const float* __restrict__ hT,
                                          const float* __restrict__ W_gate,
                                          const float* __restrict__ W_mlp,
                                          float* __restrict__ pg,
                                          float* __restrict__ pM) {
    int b = threadIdx.x;
    int c = blockIdx.x >> 3;
    int s = blockIdx.x & 7;
    int d0 = s * 64;
    float gs = 0.f, am[10] = {};
    for (int d = 0; d < 64; ++d) {
        int dd = d0 + d;
        float x = hT[(c * 512 + dd) * 128 + b];
        gs = fmaf(x, W_gate[c * 512 + dd], gs);
        const float* wm = &W_mlp[dd * 10];
        #pragma unroll
        for (int k = 0; k < 10; ++k) am[k] = fmaf(x, wm[k], am[k]);
    }
    pg[(s * 5 + c) * 128 + b] = gs;
    #pragma unroll
    for (int k = 0; k < 10; ++k) pM[((s * 5 + c) * 10 + k) * 128 + b] = am[k];
}

__global__ __launch_bounds__(128) void kRG(const float* __restrict__ pg,
                                           const float* __restrict__ pM,
                                           const float* __restrict__ b_gate,
                                           float* __restrict__ p,
                                           float* __restrict__ M,
                                           float* __restrict__ out_pt) {
    int b = threadIdx.x;
    int c = blockIdx.x;               // 5
    float gate = b_gate[c];
    #pragma unroll
    for (int s = 0; s < 8; ++s) gate += pg[(s * 5 + c) * 128 + b];
    float pv = 1.f / (1.f + __expf(-gate));
    p[b * 5 + c] = pv;
    out_pt[b * 5 + c] = pv;           // p_t output (B,C,1)
    #pragma unroll
    for (int k = 0; k < 10; ++k) {
        float acc = 0.f;
        #pragma unroll
        for (int s = 0; s < 8; ++s) acc += pM[((s * 5 + c) * 10 + k) * 128 + b];
        M[(b * 5 + c) * 10 + k] = acc;
    }
}

// ---------------- fused epilogue over (b,t) --------------------------------------
// g = sigmoid((2p-1 + gum1-gum0)/tau); g_t out; v = softmax_c(g);
// lg[k] = relu(sum_c v*M + b_mlp); r_s = softmax_k(lg) written to (T,B,K).
__global__ __launch_bounds__(256) void kC(const float* __restrict__ gumbel,
                                          const float* __restrict__ p,
                                          const float* __restrict__ M,
                                          const float* __restrict__ b_mlp,
                                          float* __restrict__ out_rs,
                                          float* __restrict__ out_gt) {
    int t = blockIdx.x * 256 + threadIdx.x;
    int b = blockIdx.y;
    if (t >= 1000) return;
    float ex[5], ssum = 0.f;
    #pragma unroll
    for (int c = 0; c < 5; ++c) {
        float2 gu = *(const float2*)&gumbel[(size_t)(((b * 5 + c) * 1000) + t) * 2];
        float pp  = p[b * 5 + c];
        float arg = (2.f * pp - 1.f + gu.y - gu.x) * 10.0f;  // /tau
        float gt  = 1.f / (1.f + __expf(-arg));
        out_gt[(b * 5 + c) * 1000 + t] = gt;
        float e = __expf(gt);
        ex[c] = e; ssum += e;
    }
    float inv = 1.f / ssum;
    float lg[10];
    #pragma unroll
    for (int k = 0; k < 10; ++k) lg[k] = b_mlp[k];
    #pragma unroll
    for (int c = 0; c < 5; ++c) {
        float v = ex[c] * inv;
        const float* m = &M[(b * 5 + c) * 10];
        #pragma unroll
        for (int k = 0; k < 10; ++k) lg[k] = fmaf(v, m[k], lg[k]);
    }
    float mx = 0.f;
    #pragma unroll
    for (int k = 0; k < 10; ++k) { lg[k] = fmaxf(lg[k], 0.f); mx = fmaxf(mx, lg[k]); }
    float se = 0.f;
    #pragma unroll
    for (int k = 0; k < 10; ++k) { lg[k] = __expf(lg[k] - mx); se += lg[k]; }
    float invs = 1.f / se;
    float2 outv[5];
    #pragma unroll
    for (int k = 0; k < 10; ++k) ((float*)outv)[k] = lg[k] * invs;
    float2* dst = (float2*)&out_rs[(size_t)t * 1280 + b * 10];
    #pragma unroll
    for (int j = 0; j < 5; ++j) dst[j] = outv[j];
}

extern "C" void kernel_launch(void* const* d_in, const int* in_sizes, int n_in,
                              void* d_out, int out_size, void* d_ws, size_t ws_size,
                              hipStream_t stream) {
    const float* feats   = (const float*)d_in[0];
    const float* W_adapt = (const float*)d_in[1];
    const float* b_adapt = (const float*)d_in[2];
    const float* W_ch    = (const float*)d_in[3];
    const float* b_ch    = (const float*)d_in[4];
    const float* W_gate  = (const float*)d_in[5];
    const float* b_gate  = (const float*)d_in[6];
    const float* W_mlp   = (const float*)d_in[7];
    const float* b_mlp   = (const float*)d_in[8];
    const float* gumbel  = (const float*)d_in[9];

    float* out    = (float*)d_out;
    float* out_rs = out;                  // (T,B,K)  1,280,000
    float* out_gt = out + 1280000;        // (B,C,T)    640,000
    float* out_pt = out + 1920000;        // (B,C,1)        640

    float* ws     = (float*)d_ws;
    float* featsT = ws;                   // 128,000
    float* pA     = featsT + 128000;      // 524,288  (8 x 512 x 128)
    float* r_bT   = pA + 524288;          //  65,536  (512 x 128)
    float* pB     = r_bT + 65536;         // 1,310,720 (4 x 5 x 512 x 128)
    float* hT     = pB + 1310720;         // 327,680  (5 x 512 x 128)
    float* pg     = hT + 327680;          //   5,120
    float* pM     = pg + 5120;            //  51,200
    float* p      = pM + 51200;           //     640
    float* M      = p + 640;              //   6,400
    // total ~9.3 MB of d_ws

    kT <<<500,           256, 0, stream>>>(feats, featsT);
    kA <<<dim3(64, 8),   128, 0, stream>>>(featsT, W_adapt, pA);
    kRA<<<256,           256, 0, stream>>>(pA, b_adapt, r_bT);
    kB <<<dim3(32, 4, 5),128, 0, stream>>>(r_bT, W_ch, pB);
    kRB<<<1280,          256, 0, stream>>>(pB, b_ch, hT);
    kG <<<40,            128, 0, stream>>>(hT, W_gate, W_mlp, pg, pM);
    kRG<<<5,             128, 0, stream>>>(pg, pM, b_gate, p, M, out_pt);
    kC <<<dim3(4, 128),  256, 0, stream>>>(gumbel, p, M, b_mlp, out_rs, out_gt);
}

// Round 2
// 51.007 us; speedup vs baseline: 1.2847x; 1.2847x over previous
//
#include <hip/hip_runtime.h>
#include <hip/hip_bf16.h>
#include <math.h>

// B=128, F_IN=1000, D=512, K=10, C=5, T=1000, TAU=0.1
// Contraction: logits_s[b,t,k] = sum_c v[b,c,t] * M[b,c,k], M = h @ W_mlp.
// Layout: lanes->e everywhere (coalesced weights, scalar-broadcast activations).
// 5 kernels: kA (adapt partials) -> kRA (reduce+relu) -> kB (channel partials)
//            -> kG (fused reduce+relu+gate+M, wave per (b,c)) -> kC (epilogue).

// ---- adapt partials: pA[s][b][e] ; s=10 splits of 100 k, 4 b per block ----
__global__ __launch_bounds__(256) void kA(const float* __restrict__ feats,
                                          const float* __restrict__ W_adapt,
                                          float* __restrict__ pA) {
    int b0 = blockIdx.x * 4;          // 32 b-tiles
    int s  = blockIdx.y;              // 10 k-splits
    int k0 = s * 100;
    int e  = threadIdx.x;             // + e+256
    float acc[4][2] = {};
    #pragma unroll 2
    for (int k = 0; k < 100; ++k) {
        const float* w = &W_adapt[(k0 + k) * 512 + e];
        float w0 = w[0], w1 = w[256];
        #pragma unroll
        for (int j = 0; j < 4; ++j) {
            float f = feats[(b0 + j) * 1000 + k0 + k];   // wave-uniform
            acc[j][0] = fmaf(f, w0, acc[j][0]);
            acc[j][1] = fmaf(f, w1, acc[j][1]);
        }
    }
    #pragma unroll
    for (int j = 0; j < 4; ++j) {
        pA[(s * 128 + b0 + j) * 512 + e]       = acc[j][0];
        pA[(s * 128 + b0 + j) * 512 + e + 256] = acc[j][1];
    }
}

// ---- reduce 10 partials + bias + relu -> r_b[b][e] ----
__global__ __launch_bounds__(256) void kRA(const float* __restrict__ pA,
                                           const float* __restrict__ b_adapt,
                                           float* __restrict__ r_b) {
    int i = blockIdx.x * 256 + threadIdx.x;   // < 65536
    float acc = b_adapt[i & 511];
    #pragma unroll
    for (int s = 0; s < 10; ++s) acc += pA[s * 65536 + i];
    r_b[i] = fmaxf(acc, 0.f);
}

// ---- channel partials: pB[s][c][b][e] ; 8 b per block, 4 d-splits, e-halves ----
__global__ __launch_bounds__(256) void kB(const float* __restrict__ r_b,
                                          const float* __restrict__ W_ch,
                                          float* __restrict__ pB) {
    int bt = blockIdx.x >> 1, eh = blockIdx.x & 1;   // 16 bt x 2 eh
    int s  = blockIdx.y;                             // 4 d-splits
    int c  = blockIdx.z;                             // 5
    int e  = eh * 256 + threadIdx.x;
    int b0 = bt * 8, d0 = s * 128;
    const float* wb = &W_ch[((size_t)c * 512 + d0) * 512 + e];
    const float* rb = &r_b[b0 * 512 + d0];
    float acc[8] = {};
    #pragma unroll 4
    for (int d = 0; d < 128; ++d) {
        float w = wb[d * 512];
        #pragma unroll
        for (int j = 0; j < 8; ++j)
            acc[j] = fmaf(rb[j * 512 + d], w, acc[j]);   // rb: wave-uniform
    }
    #pragma unroll
    for (int j = 0; j < 8; ++j)
        pB[((s * 5 + c) * 128 + b0 + j) * 512 + e] = acc[j];
}

// ---- fused: reduce pB + bias + relu -> h (in regs), gate sigmoid, M = h@W_mlp
//      one wave per (b,c); 640 pairs -> 160 blocks x 4 waves ----
__global__ __launch_bounds__(256) void kG(const float* __restrict__ pB,
                                          const float* __restrict__ b_ch,
                                          const float* __restrict__ W_gate,
                                          const float* __restrict__ W_mlp,
                                          const float* __restrict__ b_gate,
                                          float* __restrict__ p,
                                          float* __restrict__ M,
                                          float* __restrict__ out_pt) {
    int wv = threadIdx.x >> 6, lane = threadIdx.x & 63;
    int pair = blockIdx.x * 4 + wv;    // < 640
    int b = pair / 5, c = pair % 5;
    float gs = 0.f, am[10] = {};
    #pragma unroll
    for (int i = 0; i < 8; ++i) {
        int e = i * 64 + lane;
        float hs = b_ch[c * 512 + e];
        #pragma unroll
        for (int s = 0; s < 4; ++s) hs += pB[((s * 5 + c) * 128 + b) * 512 + e];
        float h = fmaxf(hs, 0.f);
        gs = fmaf(h, W_gate[c * 512 + e], gs);
        const float* wm = &W_mlp[e * 10];
        #pragma unroll
        for (int k = 0; k < 10; ++k) am[k] = fmaf(h, wm[k], am[k]);
    }
    #pragma unroll
    for (int off = 32; off; off >>= 1) {
        gs += __shfl_xor(gs, off);
        #pragma unroll
        for (int k = 0; k < 10; ++k) am[k] += __shfl_xor(am[k], off);
    }
    if (lane == 0) {
        float pv = 1.f / (1.f + __expf(-(gs + b_gate[c])));
        p[b * 5 + c] = pv;
        out_pt[b * 5 + c] = pv;
        #pragma unroll
        for (int k = 0; k < 10; ++k) M[(b * 5 + c) * 10 + k] = am[k];
    }
}

// ---- fused epilogue over (b,t): gumbel-sigmoid, softmax_c, MLP, softmax_k ----
__global__ __launch_bounds__(256) void kC(const float* __restrict__ gumbel,
                                          const float* __restrict__ p,
                                          const float* __restrict__ M,
                                          const float* __restrict__ b_mlp,
                                          float* __restrict__ out_rs,
                                          float* __restrict__ out_gt) {
    int t = blockIdx.x * 256 + threadIdx.x;
    int b = blockIdx.y;
    if (t >= 1000) return;
    float ex[5], ssum = 0.f;
    #pragma unroll
    for (int c = 0; c < 5; ++c) {
        float2 gu = *(const float2*)&gumbel[(size_t)(((b * 5 + c) * 1000) + t) * 2];
        float pp  = p[b * 5 + c];
        float arg = (2.f * pp - 1.f + gu.y - gu.x) * 10.0f;  // /tau
        float gt  = 1.f / (1.f + __expf(-arg));
        out_gt[(b * 5 + c) * 1000 + t] = gt;
        float e = __expf(gt);
        ex[c] = e; ssum += e;
    }
    float inv = 1.f / ssum;
    float lg[10];
    #pragma unroll
    for (int k = 0; k < 10; ++k) lg[k] = b_mlp[k];
    #pragma unroll
    for (int c = 0; c < 5; ++c) {
        float v = ex[c] * inv;
        const float* m = &M[(b * 5 + c) * 10];
        #pragma unroll
        for (int k = 0; k < 10; ++k) lg[k] = fmaf(v, m[k], lg[k]);
    }
    float mx = 0.f;
    #pragma unroll
    for (int k = 0; k < 10; ++k) { lg[k] = fmaxf(lg[k], 0.f); mx = fmaxf(mx, lg[k]); }
    float se = 0.f;
    #pragma unroll
    for (int k = 0; k < 10; ++k) { lg[k] = __expf(lg[k] - mx); se += lg[k]; }
    float invs = 1.f / se;
    float2 outv[5];
    #pragma unroll
    for (int k = 0; k < 10; ++k) ((float*)outv)[k] = lg[k] * invs;
    float2* dst = (float2*)&out_rs[(size_t)t * 1280 + b * 10];
    #pragma unroll
    for (int j = 0; j < 5; ++j) dst[j] = outv[j];
}

extern "C" void kernel_launch(void* const* d_in, const int* in_sizes, int n_in,
                              void* d_out, int out_size, void* d_ws, size_t ws_size,
                              hipStream_t stream) {
    const float* feats   = (const float*)d_in[0];
    const float* W_adapt = (const float*)d_in[1];
    const float* b_adapt = (const float*)d_in[2];
    const float* W_ch    = (const float*)d_in[3];
    const float* b_ch    = (const float*)d_in[4];
    const float* W_gate  = (const float*)d_in[5];
    const float* b_gate  = (const float*)d_in[6];
    const float* W_mlp   = (const float*)d_in[7];
    const float* b_mlp   = (const float*)d_in[8];
    const float* gumbel  = (const float*)d_in[9];

    float* out    = (float*)d_out;
    float* out_rs = out;                  // (T,B,K)  1,280,000
    float* out_gt = out + 1280000;        // (B,C,T)    640,000
    float* out_pt = out + 1920000;        // (B,C,1)        640

    float* ws  = (float*)d_ws;
    float* pA  = ws;                      // 10*128*512 = 655,360
    float* r_b = pA + 655360;             // 128*512    =  65,536
    float* pB  = r_b + 65536;             // 4*5*128*512 = 1,310,720
    float* p   = pB + 1310720;            //       640
    float* M   = p + 640;                 //     6,400

    kA <<<dim3(32, 10),   256, 0, stream>>>(feats, W_adapt, pA);
    kRA<<<256,            256, 0, stream>>>(pA, b_adapt, r_b);
    kB <<<dim3(32, 4, 5), 256, 0, stream>>>(r_b, W_ch, pB);
    kG <<<160,            256, 0, stream>>>(pB, b_ch, W_gate, W_mlp, b_gate, p, M, out_pt);
    kC <<<dim3(4, 128),   256, 0, stream>>>(gumbel, p, M, b_mlp, out_rs, out_gt);
}